// Round 10
// baseline (325.298 us; speedup 1.0000x reference)
//
#include <hip/hip_runtime.h>
#include <math.h>

#define N_NODES   32768
#define NUM_EDGES 524288
#define NUM_GRAPHS 32
#define PER_G     1024
#define C         128
#define D_IN      144
#define C_MID     80
#define C_OUT     64
#define NL        3
#define NBINS     32
#define CSTRIDE   64    // fixed CSR slots per node (mean deg 16, max ~40)

// ---------------- workspace layout (byte offsets) ----------------
#define WS_H    0                         // N*C f32       16777216
#define WS_XL   16777216                  // N*C bf16       8388608
#define WS_XR   25165824                  // N*C bf16       8388608
#define WS_CSR  33554432                  // N*64 i32       8388608
// ---- contiguous zeroed region ----
#define WS_CUR  41943040                  // N i32           131072
#define WS_PART 42074112                  // 32*256 f32       32768
#define WS_CS   42106880                  // 320 f32           1280
#define WS_KL   42108160                  // 1 f32                4
#define WS_ZERO_BASE WS_CUR
#define WS_ZERO_SIZE (42108164 - 41943040)
// ----------------------------------
#define WS_SC   42108928                  // 128 f32
#define WS_SH   42109440                  // 128 f32
#define WS_S1   42109952                  // 32768*10 f32   1310720
#define WS_PP   43420672                  // 1024*10*128 f32 5242880
#define WS_X1   48663552                  // 320*80 f32      102400
#define WS_WINT 48765952                  // 128*320 B bf16 W_in^T swizzled   40960
#define WS_WLRT 48806912                  // 6 * 128*256 B bf16 Wl/Wr^T      196608

using short8 = __attribute__((ext_vector_type(8))) short;
using f32x4  = __attribute__((ext_vector_type(4))) float;

__device__ __forceinline__ float wave_sum(float v) {
  #pragma unroll
  for (int m = 1; m < 64; m <<= 1) v += __shfl_xor(v, m, 64);
  return v;
}

__device__ __forceinline__ float lrelu2(float v) { return fmaxf(v, 0.2f * v); }

__device__ __forceinline__ unsigned short f2bf(float f) {
  union { float f; unsigned u; } c; c.f = f;
  unsigned r = (c.u + 0x7FFFu + ((c.u >> 16) & 1u)) >> 16;
  return (unsigned short)r;
}
__device__ __forceinline__ float bflo(unsigned u) {
  union { unsigned u; float f; } c; c.u = u << 16; return c.f;
}
__device__ __forceinline__ float bfhi(unsigned u) {
  union { unsigned u; float f; } c; c.u = u & 0xFFFF0000u; return c.f;
}

// ---------------- CSR build: single pass, fixed stride ----------------
__global__ void k_fill(const int* __restrict__ src, const int* __restrict__ dst,
                       int* __restrict__ cur, int* __restrict__ csr) {
  int e = blockIdx.x * 256 + threadIdx.x;
  if (e < NUM_EDGES) {
    int d = dst[e];
    int p = atomicAdd(&cur[d], 1);
    if (p < CSTRIDE) csr[d * CSTRIDE + p] = src[e];
  }
}

// ---------------- pre-convert weights to bf16 W^T, pre-swizzled LDS layout ----------------
__global__ __launch_bounds__(256) void k_prep(const float* __restrict__ W_in,
    const float* __restrict__ Wl, const float* __restrict__ Wr,
    char* __restrict__ winT, char* __restrict__ wlrT) {
  int bid = blockIdx.x;
  int tid = threadIdx.x;
  int col = tid & 127, hh = tid >> 7;
  if (bid < 4) {
    int q = bid;
    float w0[10], w1[10];
    #pragma unroll
    for (int i = 0; i < 10; i++) {
      int p = 2 * (q * 10 + i) + hh;
      w0[i] = (2 * p < D_IN) ? W_in[(size_t)(2 * p) * C + col] : 0.f;
      w1[i] = (2 * p + 1 < D_IN) ? W_in[(size_t)(2 * p + 1) * C + col] : 0.f;
    }
    #pragma unroll
    for (int i = 0; i < 10; i++) {
      int p = 2 * (q * 10 + i) + hh;
      unsigned pkv = ((unsigned)f2bf(w1[i]) << 16) | f2bf(w0[i]);
      int byte = col * 320 + ((4 * p) ^ (((col >> 1) & 3) << 4));
      *(unsigned*)(winT + byte) = pkv;
    }
  } else {
    int id = bid - 4;
    int m = id >> 2;
    int q = id & 3;
    int l = m >> 1, r = m & 1;
    const float* W = (r ? Wr : Wl) + (size_t)l * C * C;
    char* dst = wlrT + (size_t)m * 32768;
    float w0[8], w1[8];
    #pragma unroll
    for (int i = 0; i < 8; i++) {
      int p = 2 * (q * 8 + i) + hh;
      w0[i] = W[(size_t)(2 * p) * C + col];
      w1[i] = W[(size_t)(2 * p + 1) * C + col];
    }
    #pragma unroll
    for (int i = 0; i < 8; i++) {
      int p = 2 * (q * 8 + i) + hh;
      unsigned pkv = ((unsigned)f2bf(w1[i]) << 16) | f2bf(w0[i]);
      int byte = col * 256 + ((4 * p) ^ ((col & 7) << 4));
      *(unsigned*)(dst + byte) = pkv;
    }
  }
}

// ---------------- h = x @ W_in + b_in via MFMA + fused BN partial stats ----------------
__global__ __launch_bounds__(256) void k_lin_mfma(const float* __restrict__ x,
    const char* __restrict__ winT, const float* __restrict__ bias,
    float* __restrict__ h, float* __restrict__ part) {
  __shared__ __align__(16) char smem[61440];
  __shared__ float lsum[128];
  __shared__ float lsum2[128];
  char* tA = smem;
  char* tB = smem + 20480;
  int n0 = blockIdx.x * 64;
  int tid = threadIdx.x;
  if (tid < 128) { lsum[tid] = 0.f; lsum2[tid] = 0.f; }
  {
    float4 xv[10];
    #pragma unroll
    for (int k = 0; k < 10; k++) {
      int idx = k * 256 + tid;
      int row = idx / 40, j = idx - row * 40;
      xv[k] = (j < 36) ? *(const float4*)&x[(size_t)(n0 + row) * D_IN + 4 * j]
                       : (float4){0.f, 0.f, 0.f, 0.f};
    }
    #pragma unroll
    for (int k = 0; k < 10; k++) {
      int idx = k * 256 + tid;
      int row = idx / 40, j = idx - row * 40;
      uint2 pk;
      pk.x = ((unsigned)f2bf(xv[k].y) << 16) | f2bf(xv[k].x);
      pk.y = ((unsigned)f2bf(xv[k].w) << 16) | f2bf(xv[k].z);
      int byte = row * 320 + ((8 * j) ^ (((row >> 1) & 3) << 4));
      *(uint2*)(tA + byte) = pk;
    }
  }
  {
    const uint4* src = (const uint4*)winT;
    uint4* d = (uint4*)tB;
    uint4 v[10];
    #pragma unroll
    for (int k = 0; k < 10; k++) v[k] = src[k * 256 + tid];
    #pragma unroll
    for (int k = 0; k < 10; k++) d[k * 256 + tid] = v[k];
  }
  __syncthreads();
  int l = tid & 63, w = tid >> 6;
  f32x4 acc[8];
  #pragma unroll
  for (int f = 0; f < 8; f++) acc[f] = (f32x4){0.f, 0.f, 0.f, 0.f};
  int arow = w * 16 + (l & 15);
  #pragma unroll
  for (int ks = 0; ks < 5; ks++) {
    int kb = ks * 64 + (l >> 4) * 16;
    short8 a = *(const short8*)(tA + arow * 320 + (kb ^ (((arow >> 1) & 3) << 4)));
    #pragma unroll
    for (int f = 0; f < 8; f++) {
      int col = f * 16 + (l & 15);
      short8 b = *(const short8*)(tB + col * 320 + (kb ^ (((col >> 1) & 3) << 4)));
      acc[f] = __builtin_amdgcn_mfma_f32_16x16x32_bf16(a, b, acc[f], 0, 0, 0);
    }
  }
  int rowb = n0 + w * 16 + (l >> 4) * 4;
  #pragma unroll
  for (int f = 0; f < 8; f++) {
    int col = f * 16 + (l & 15);
    float bv = bias[col];
    float s = 0.f, s2 = 0.f;
    #pragma unroll
    for (int r = 0; r < 4; r++) {
      float v = acc[f][r] + bv;
      h[(size_t)(rowb + r) * C + col] = v;
      s += v; s2 += v * v;
    }
    s  += __shfl_xor(s, 16, 64);  s  += __shfl_xor(s, 32, 64);
    s2 += __shfl_xor(s2, 16, 64); s2 += __shfl_xor(s2, 32, 64);
    if (l < 16) {
      atomicAdd(&lsum[col], s);
      atomicAdd(&lsum2[col], s2);
    }
  }
  __syncthreads();
  if (tid < 128) {
    int bin = blockIdx.x & (NBINS - 1);
    atomicAdd(&part[bin * 256 + tid], lsum[tid]);
    atomicAdd(&part[bin * 256 + 128 + tid], lsum2[tid]);
  }
}

// ---------------- BN finalize: reduce 32 bins -> sc/sh, re-zero bins ----------------
__global__ __launch_bounds__(256) void k_bn_fin(float* __restrict__ part,
    const float* __restrict__ gamma, const float* __restrict__ beta,
    float* __restrict__ sc, float* __restrict__ sh) {
  int tid = threadIdx.x;
  if (tid < 128) {
    double S = 0.0, S2 = 0.0;
    for (int b = 0; b < NBINS; b++) {
      S += (double)part[b * 256 + tid];
      S2 += (double)part[b * 256 + 128 + tid];
    }
    double m = S / (double)N_NODES;
    double var = S2 / (double)N_NODES - m * m;
    float rsig = (float)(1.0 / sqrt(var + 1e-5));
    float scv = rsig * gamma[tid];
    sc[tid] = scv;
    sh[tid] = beta[tid] - (float)m * scv;
  }
  __syncthreads();
  for (int i = tid; i < NBINS * 256; i += 256) part[i] = 0.f;
}

// ---------------- fused: t = leaky(bn(h)); xl = t@Wl+bl; xr = t@Wr+br ----------------
__device__ __forceinline__ void gemm_half(const char* tA, const char* tB,
    const float* bias, unsigned short* out, int n0, int tid) {
  int l = tid & 63, w = tid >> 6;
  f32x4 acc[8];
  #pragma unroll
  for (int f = 0; f < 8; f++) acc[f] = (f32x4){0.f, 0.f, 0.f, 0.f};
  int arow = w * 16 + (l & 15);
  #pragma unroll
  for (int ks = 0; ks < 4; ks++) {
    int kb = ks * 64 + (l >> 4) * 16;
    short8 a = *(const short8*)(tA + arow * 256 + (kb ^ ((arow & 7) << 4)));
    #pragma unroll
    for (int f = 0; f < 8; f++) {
      int col = f * 16 + (l & 15);
      short8 b = *(const short8*)(tB + col * 256 + (kb ^ ((col & 7) << 4)));
      acc[f] = __builtin_amdgcn_mfma_f32_16x16x32_bf16(a, b, acc[f], 0, 0, 0);
    }
  }
  int rowb = n0 + w * 16 + (l >> 4) * 4;
  #pragma unroll
  for (int f = 0; f < 8; f++) {
    int col = f * 16 + (l & 15);
    float bv = bias[col];
    #pragma unroll
    for (int r = 0; r < 4; r++)
      out[(size_t)(rowb + r) * C + col] = f2bf(acc[f][r] + bv);
  }
}

__device__ __forceinline__ void copy_B(char* tB, const char* __restrict__ WT, int tid) {
  const uint4* src = (const uint4*)WT;
  uint4* d = (uint4*)tB;
  uint4 v[8];
  #pragma unroll
  for (int k = 0; k < 8; k++) v[k] = src[k * 256 + tid];
  #pragma unroll
  for (int k = 0; k < 8; k++) d[k * 256 + tid] = v[k];
}

__global__ __launch_bounds__(256) void k_gemm_mfma(const float* __restrict__ h,
    const float* __restrict__ sc, const float* __restrict__ sh,
    const char* __restrict__ WlT, const float* __restrict__ bl,
    const char* __restrict__ WrT, const float* __restrict__ br,
    unsigned short* __restrict__ xl, unsigned short* __restrict__ xr) {
  __shared__ __align__(16) char smem[49152];
  char* tA = smem;
  char* tB = smem + 16384;
  int n0 = blockIdx.x * 64;
  int tid = threadIdx.x;
  {
    int cp = tid & 63, w4 = tid >> 6;
    float2 scv = *(const float2*)&sc[2 * cp];
    float2 shv = *(const float2*)&sh[2 * cp];
    float2 hv[16];
    #pragma unroll
    for (int t = 0; t < 16; t++)
      hv[t] = *(const float2*)&h[(size_t)(n0 + t * 4 + w4) * C + 2 * cp];
    #pragma unroll
    for (int t = 0; t < 16; t++) {
      int node = t * 4 + w4;
      float t0 = hv[t].x * scv.x + shv.x; t0 = fmaxf(t0, 0.01f * t0);
      float t1 = hv[t].y * scv.y + shv.y; t1 = fmaxf(t1, 0.01f * t1);
      unsigned pkv = ((unsigned)f2bf(t1) << 16) | f2bf(t0);
      int byte = node * 256 + ((4 * cp) ^ ((node & 7) << 4));
      *(unsigned*)(tA + byte) = pkv;
    }
  }
  copy_B(tB, WlT, tid);
  __syncthreads();
  gemm_half(tA, tB, bl, xl, n0, tid);
  __syncthreads();
  copy_B(tB, WrT, tid);
  __syncthreads();
  gemm_half(tA, tB, br, xr, n0, tid);
}

// ---------------- fused GATv2: 2 nodes/wave, defer-max softmax, optional BN stats ----------------
#define GAT_EDGE(te, ya, yb, yc, yd)                                       \
  if ((te) > m + 8.f) {                                                    \
    float f_ = __expf(m - (te));                                           \
    ssum = fmaf(ssum, f_, 1.f);                                            \
    acc0 = fmaf(acc0, f_, (ya)); acc1 = fmaf(acc1, f_, (yb));              \
    acc2 = fmaf(acc2, f_, (yc)); acc3 = fmaf(acc3, f_, (yd));              \
    m = (te);                                                              \
  } else {                                                                 \
    float p_ = __expf((te) - m);                                           \
    ssum += p_;                                                            \
    acc0 = fmaf(p_, (ya), acc0); acc1 = fmaf(p_, (yb), acc1);              \
    acc2 = fmaf(p_, (yc), acc2); acc3 = fmaf(p_, (yd), acc3);              \
  }

__global__ __launch_bounds__(256) void k_gat(float* __restrict__ h,
    const unsigned* __restrict__ xlb, const unsigned* __restrict__ xrb,
    const float* __restrict__ att, const float* __restrict__ cb,
    const int* __restrict__ deg, const int* __restrict__ csr,
    float* __restrict__ part) {
  __shared__ float gsum[128];
  __shared__ float gsum2[128];
  int tid = threadIdx.x;
  if (part) {
    if (tid < 128) { gsum[tid] = 0.f; gsum2[tid] = 0.f; }
    __syncthreads();
  }
  int lane = tid & 63;
  int w = tid >> 6;
  int half = lane >> 5;
  int q = lane & 31;
  int node = blockIdx.x * 8 + w * 2 + half;
  float4 a = *(const float4*)&att[q * 4];
  uint2 ur = *(const uint2*)&xrb[(size_t)node * 64 + q * 2];
  float xr0 = bflo(ur.x), xr1 = bfhi(ur.x), xr2 = bflo(ur.y), xr3 = bfhi(ur.y);
  uint2 us = *(const uint2*)&xlb[(size_t)node * 64 + q * 2];
  float acc0 = bflo(us.x), acc1 = bfhi(us.x), acc2 = bflo(us.y), acc3 = bfhi(us.y);
  float p0 = lrelu2(acc0 + xr0) * a.x + lrelu2(acc1 + xr1) * a.y
           + lrelu2(acc2 + xr2) * a.z + lrelu2(acc3 + xr3) * a.w;
  #pragma unroll
  for (int mm = 1; mm < 32; mm <<= 1) p0 += __shfl_xor(p0, mm, 64);
  float m = p0;
  float ssum = 1.f;
  int o = node * CSTRIDE;
  int dg = min(deg[node], CSTRIDE);
  int dgmax = max(dg, __shfl_xor(dg, 32, 64));
  for (int j = 0; j < dgmax; j += 4) {
    int i0 = o + ((j + 0 < dg) ? j + 0 : 0);
    int i1 = o + ((j + 1 < dg) ? j + 1 : 0);
    int i2 = o + ((j + 2 < dg) ? j + 2 : 0);
    int i3 = o + ((j + 3 < dg) ? j + 3 : 0);
    int s0 = csr[i0], s1 = csr[i1], s2 = csr[i2], s3 = csr[i3];
    uint2 u0 = *(const uint2*)&xlb[(size_t)s0 * 64 + q * 2];
    uint2 u1 = *(const uint2*)&xlb[(size_t)s1 * 64 + q * 2];
    uint2 u2 = *(const uint2*)&xlb[(size_t)s2 * 64 + q * 2];
    uint2 u3 = *(const uint2*)&xlb[(size_t)s3 * 64 + q * 2];
    float y00 = bflo(u0.x), y01 = bfhi(u0.x), y02 = bflo(u0.y), y03 = bfhi(u0.y);
    float y10 = bflo(u1.x), y11 = bfhi(u1.x), y12 = bflo(u1.y), y13 = bfhi(u1.y);
    float y20 = bflo(u2.x), y21 = bfhi(u2.x), y22 = bflo(u2.y), y23 = bfhi(u2.y);
    float y30 = bflo(u3.x), y31 = bfhi(u3.x), y32 = bflo(u3.y), y33 = bfhi(u3.y);
    float t0 = lrelu2(y00 + xr0) * a.x + lrelu2(y01 + xr1) * a.y
             + lrelu2(y02 + xr2) * a.z + lrelu2(y03 + xr3) * a.w;
    float t1 = lrelu2(y10 + xr0) * a.x + lrelu2(y11 + xr1) * a.y
             + lrelu2(y12 + xr2) * a.z + lrelu2(y13 + xr3) * a.w;
    float t2 = lrelu2(y20 + xr0) * a.x + lrelu2(y21 + xr1) * a.y
             + lrelu2(y22 + xr2) * a.z + lrelu2(y23 + xr3) * a.w;
    float t3 = lrelu2(y30 + xr0) * a.x + lrelu2(y31 + xr1) * a.y
             + lrelu2(y32 + xr2) * a.z + lrelu2(y33 + xr3) * a.w;
    #pragma unroll
    for (int mm = 1; mm < 32; mm <<= 1) {
      t0 += __shfl_xor(t0, mm, 64);
      t1 += __shfl_xor(t1, mm, 64);
      t2 += __shfl_xor(t2, mm, 64);
      t3 += __shfl_xor(t3, mm, 64);
    }
    t0 = (j + 0 < dg) ? t0 : -1e30f;
    t1 = (j + 1 < dg) ? t1 : -1e30f;
    t2 = (j + 2 < dg) ? t2 : -1e30f;
    t3 = (j + 3 < dg) ? t3 : -1e30f;
    GAT_EDGE(t0, y00, y01, y02, y03);
    GAT_EDGE(t1, y10, y11, y12, y13);
    GAT_EDGE(t2, y20, y21, y22, y23);
    GAT_EDGE(t3, y30, y31, y32, y33);
  }
  float inv = 1.f / ssum;
  float4 cbv = *(const float4*)&cb[q * 4];
  float4 hv = *(float4*)&h[(size_t)node * C + q * 4];
  hv.x += acc0 * inv + cbv.x;
  hv.y += acc1 * inv + cbv.y;
  hv.z += acc2 * inv + cbv.z;
  hv.w += acc3 * inv + cbv.w;
  *(float4*)&h[(size_t)node * C + q * 4] = hv;
  if (part) {
    atomicAdd(&gsum[q * 4 + 0], hv.x);
    atomicAdd(&gsum[q * 4 + 1], hv.y);
    atomicAdd(&gsum[q * 4 + 2], hv.z);
    atomicAdd(&gsum[q * 4 + 3], hv.w);
    atomicAdd(&gsum2[q * 4 + 0], hv.x * hv.x);
    atomicAdd(&gsum2[q * 4 + 1], hv.y * hv.y);
    atomicAdd(&gsum2[q * 4 + 2], hv.z * hv.z);
    atomicAdd(&gsum2[q * 4 + 3], hv.w * hv.w);
    __syncthreads();
    if (tid < 128) {
      int bin = blockIdx.x & (NBINS - 1);
      atomicAdd(&part[bin * 256 + tid], gsum[tid]);
      atomicAdd(&part[bin * 256 + 128 + tid], gsum2[tid]);
    }
  }
}

// ---------------- mem-pool 1 ----------------
__global__ __launch_bounds__(320) void k_mem1(const float* __restrict__ h,
    const float* __restrict__ K1, float* __restrict__ S1, float* __restrict__ colsum) {
  __shared__ float dd[64 * 51];
  __shared__ float kn[50];
  int tid = threadIdx.x;
  int lane = tid & 63;
  int w = tid >> 6;
  int n0 = blockIdx.x * 64;
  if (tid < 50) {
    const float4* kr = reinterpret_cast<const float4*>(K1 + tid * C);
    float s = 0.f;
    for (int q = 0; q < 32; q++) {
      float4 kv = kr[q];
      s += kv.x * kv.x + kv.y * kv.y + kv.z * kv.z + kv.w * kv.w;
    }
    kn[tid] = s;
  }
  int wu = __builtin_amdgcn_readfirstlane(w);
  const float4* x4 = reinterpret_cast<const float4*>(h + (size_t)(n0 + lane) * C);
  const float4* K4 = reinterpret_cast<const float4*>(K1);
  float acc[10];
  #pragma unroll
  for (int it = 0; it < 10; it++) acc[it] = 0.f;
  float xn = 0.f;
  for (int q = 0; q < 32; q += 2) {
    float4 xa = x4[q], xb = x4[q + 1];
    xn += xa.x * xa.x + xa.y * xa.y + xa.z * xa.z + xa.w * xa.w
        + xb.x * xb.x + xb.y * xb.y + xb.z * xb.z + xb.w * xb.w;
    #pragma unroll
    for (int it = 0; it < 10; it++) {
      int j = wu + 5 * it;
      float4 ka = K4[j * 32 + q], kb = K4[j * 32 + q + 1];
      acc[it] += xa.x * ka.x + xa.y * ka.y + xa.z * ka.z + xa.w * ka.w
               + xb.x * kb.x + xb.y * kb.y + xb.z * kb.z + xb.w * kb.w;
    }
  }
  #pragma unroll
  for (int it = 0; it < 10; it++) dd[lane * 51 + wu + 5 * it] = acc[it];
  __syncthreads();
  if (tid < 64) {
    float sn[10];
    #pragma unroll
    for (int k = 0; k < 10; k++) sn[k] = 0.f;
    #pragma unroll
    for (int hd = 0; hd < 5; hd++) {
      float sh_[10]; float hs = 0.f;
      #pragma unroll
      for (int k = 0; k < 10; k++) {
        int j = hd * 10 + k;
        float dist = xn + kn[j] - 2.f * dd[tid * 51 + j];
        float s = 1.f / (1.f + dist);
        sh_[k] = s; hs += s;
      }
      float inv = 1.f / hs;
      #pragma unroll
      for (int k = 0; k < 10; k++) sn[k] += sh_[k] * inv;
    }
    int b = n0 >> 10;
    #pragma unroll
    for (int k = 0; k < 10; k++) {
      float v = 0.2f * sn[k];
      S1[(n0 + tid) * 10 + k] = v;
      float vs = wave_sum(v);
      if (tid == 0) atomicAdd(&colsum[b * 10 + k], vs);
    }
  }
}

// ---------------- pooled features: partial S1^T @ xd ----------------
__global__ __launch_bounds__(128) void k_pool1a(const float* __restrict__ h,
    const float* __restrict__ S1, float* __restrict__ pp) {
  int b = blockIdx.x >> 5, ch = blockIdx.x & 31;
  int c = threadIdx.x;
  float acc[10];
  #pragma unroll
  for (int k = 0; k < 10; k++) acc[k] = 0.f;
  int n0 = ch * 32;
  for (int n = 0; n < 32; n++) {
    int i = b * PER_G + n0 + n;
    float xv = h[(size_t)i * C + c];
    #pragma unroll
    for (int k = 0; k < 10; k++) acc[k] += S1[i * 10 + k] * xv;
  }
  #pragma unroll
  for (int k = 0; k < 10; k++) pp[(size_t)((b * 32 + ch) * 10 + k) * C + c] = acc[k];
}

// ---------------- reduce partials, apply Wm1 + leaky -> x1 ----------------
__global__ __launch_bounds__(128) void k_pool1b(const float* __restrict__ pp,
    const float* __restrict__ Wm1, float* __restrict__ x1) {
  int bk = blockIdx.x; int b = bk / 10; int k = bk - b * 10;
  int c = threadIdx.x;
  __shared__ float red[C];
  float r = 0.f;
  for (int ch = 0; ch < 32; ch++) r += pp[(size_t)((b * 32 + ch) * 10 + k) * C + c];
  red[c] = r;
  __syncthreads();
  if (c < C_MID) {
    float o = 0.f;
    for (int mIdx = 0; mIdx < C; mIdx++) o += red[mIdx] * Wm1[mIdx * C_MID + c];
    o = fmaxf(o, 0.01f * o);
    x1[bk * C_MID + c] = o;
  }
}

// ---------------- KL(S1) ----------------
__global__ __launch_bounds__(256) void k_kl1(const float* __restrict__ S1,
    const float* __restrict__ colsum, float* __restrict__ kl) {
  int i = blockIdx.x * 256 + threadIdx.x;
  int b = i >> 10;
  float s[10], q[10];
  float den = 0.f;
  #pragma unroll
  for (int k = 0; k < 10; k++) {
    s[k] = S1[i * 10 + k];
    q[k] = s[k] * s[k] / colsum[b * 10 + k];
    den += q[k];
  }
  float inv = 1.f / den;
  float term = 0.f;
  #pragma unroll
  for (int k = 0; k < 10; k++) {
    float P = fmaxf(q[k] * inv, 1e-15f);
    float Sc = fmaxf(s[k], 1e-15f);
    term += P * (logf(P) - logf(Sc));
  }
  term *= (1.f / (float)NUM_GRAPHS);
  term = wave_sum(term);
  if ((threadIdx.x & 63) == 0) atomicAdd(kl, term);
}

// ---------------- mem-pool 2 (S2==1) + log_softmax + kl write ----------------
__global__ __launch_bounds__(128) void k_mem2(const float* __restrict__ x1,
    const float* __restrict__ Wm2, const float* __restrict__ kl, float* __restrict__ out) {
  int b = blockIdx.x;
  __shared__ float t80[C_MID];
  int tid = threadIdx.x;
  if (tid < C_MID) {
    float s = 0.f;
    #pragma unroll
    for (int k = 0; k < 10; k++) s += x1[(b * 10 + k) * C_MID + tid];
    t80[tid] = s;
  }
  __syncthreads();
  if (tid < C_OUT) {
    float o = 0.f;
    for (int mIdx = 0; mIdx < C_MID; mIdx++) o += t80[mIdx] * Wm2[mIdx * C_OUT + tid];
    float mx = o;
    #pragma unroll
    for (int d = 1; d < 64; d <<= 1) mx = fmaxf(mx, __shfl_xor(mx, d, 64));
    float p = expf(o - mx);
    float sum = p;
    #pragma unroll
    for (int d = 1; d < 64; d <<= 1) sum += __shfl_xor(sum, d, 64);
    out[b * C_OUT + tid] = o - mx - logf(sum);
  }
  if (b == 0 && tid == 127) out[NUM_GRAPHS * C_OUT] = kl[0];
}

extern "C" void kernel_launch(void* const* d_in, const int* in_sizes, int n_in,
                              void* d_out, int out_size, void* d_ws, size_t ws_size,
                              hipStream_t stream) {
  const float* x    = (const float*)d_in[0];
  const int*   ei   = (const int*)d_in[1];
  const float* W_in = (const float*)d_in[3];
  const float* b_in = (const float*)d_in[4];
  const float* bn_g = (const float*)d_in[5];
  const float* bn_b = (const float*)d_in[6];
  const float* Wl   = (const float*)d_in[7];
  const float* bl   = (const float*)d_in[8];
  const float* Wr   = (const float*)d_in[9];
  const float* br   = (const float*)d_in[10];
  const float* att  = (const float*)d_in[11];
  const float* cb   = (const float*)d_in[12];
  const float* K1   = (const float*)d_in[13];
  const float* Wm1  = (const float*)d_in[14];
  const float* Wm2  = (const float*)d_in[16];
  float* out = (float*)d_out;

  char* ws = (char*)d_ws;
  float* h    = (float*)(ws + WS_H);
  unsigned short* xlp = (unsigned short*)(ws + WS_XL);
  unsigned short* xrp = (unsigned short*)(ws + WS_XR);
  int*   csr  = (int*)(ws + WS_CSR);
  int*   cur  = (int*)(ws + WS_CUR);
  float* part = (float*)(ws + WS_PART);
  float* scv  = (float*)(ws + WS_SC);
  float* shv  = (float*)(ws + WS_SH);
  float* S1p  = (float*)(ws + WS_S1);
  float* cs   = (float*)(ws + WS_CS);
  float* pp   = (float*)(ws + WS_PP);
  float* x1p  = (float*)(ws + WS_X1);
  float* klp  = (float*)(ws + WS_KL);
  char*  winT = ws + WS_WINT;
  char*  wlrT = ws + WS_WLRT;

  const int* srcp = ei;
  const int* dstp = ei + NUM_EDGES;

  hipMemsetAsync(ws + WS_ZERO_BASE, 0, WS_ZERO_SIZE, stream);

  k_prep<<<28, 256, 0, stream>>>(W_in, Wl, Wr, winT, wlrT);
  k_fill<<<NUM_EDGES / 256, 256, 0, stream>>>(srcp, dstp, cur, csr);

  k_lin_mfma<<<N_NODES / 64, 256, 0, stream>>>(x, winT, b_in, h, part);

  for (int l = 0; l < NL; l++) {
    k_bn_fin<<<1, 256, 0, stream>>>(part, bn_g + l * C, bn_b + l * C, scv, shv);
    k_gemm_mfma<<<N_NODES / 64, 256, 0, stream>>>(h, scv, shv,
        wlrT + (size_t)(l * 2) * 32768, bl + l * C,
        wlrT + (size_t)(l * 2 + 1) * 32768, br + l * C,
        xlp, xrp);
    k_gat<<<N_NODES / 8, 256, 0, stream>>>(h, (const unsigned*)xlp, (const unsigned*)xrp,
        att + l * C, cb + l * C, cur, csr,
        (l < NL - 1) ? part : (float*)nullptr);
  }

  k_mem1<<<N_NODES / 64, 320, 0, stream>>>(h, K1, S1p, cs);
  k_pool1a<<<NUM_GRAPHS * 32, 128, 0, stream>>>(h, S1p, pp);
  k_pool1b<<<NUM_GRAPHS * 10, 128, 0, stream>>>(pp, Wm1, x1p);
  k_kl1<<<N_NODES / 256, 256, 0, stream>>>(S1p, cs, klp);
  k_mem2<<<NUM_GRAPHS, 128, 0, stream>>>(x1p, Wm2, klp, out);
}

// Round 11
// 281.455 us; speedup vs baseline: 1.1558x; 1.1558x over previous
//
#include <hip/hip_runtime.h>
#include <math.h>

#define N_NODES   32768
#define NUM_EDGES 524288
#define NUM_GRAPHS 32
#define PER_G     1024
#define C         128
#define D_IN      144
#define C_MID     80
#define C_OUT     64
#define NL        3
#define NBINS     32

// ---------------- workspace layout (byte offsets) ----------------
#define WS_H    0                         // N*C f32       16777216
#define WS_XL   16777216                  // N*C bf16       8388608
#define WS_XR   25165824                  // N*C bf16       8388608
#define WS_CSR  33554432                  // E   i32        2097152
// ---- contiguous zeroed region ----
#define WS_DEG  35651584                  // N i32           131072
#define WS_CUR  35782656                  // N i32           131072
#define WS_PART 35913728                  // 32*256 f32       32768
#define WS_CS   35946496                  // 320 f32           1280
#define WS_KL   35947776                  // 1 f32                4
#define WS_ZERO_BASE WS_DEG
#define WS_ZERO_SIZE (35947780 - 35651584)
// ----------------------------------
#define WS_SC   35948544                  // 128 f32
#define WS_SH   35949056                  // 128 f32
#define WS_S1   35949568                  // 32768*10 f32   1310720
#define WS_PP   37260288                  // 1024*10*128 f32 5242880
#define WS_X1   42503168                  // 320*80 f32      102400
#define WS_OFF  42605568                  // N i32           131072
#define WS_WINT 42736640                  // 128*320 B bf16 W_in^T swizzled   40960
#define WS_WLRT 42777600                  // 6 * 128*256 B bf16 Wl/Wr^T      196608

using short8 = __attribute__((ext_vector_type(8))) short;
using f32x4  = __attribute__((ext_vector_type(4))) float;

__device__ __forceinline__ float wave_sum(float v) {
  #pragma unroll
  for (int m = 1; m < 64; m <<= 1) v += __shfl_xor(v, m, 64);
  return v;
}

__device__ __forceinline__ float lrelu2(float v) { return fmaxf(v, 0.2f * v); }

__device__ __forceinline__ unsigned short f2bf(float f) {
  union { float f; unsigned u; } c; c.f = f;
  unsigned r = (c.u + 0x7FFFu + ((c.u >> 16) & 1u)) >> 16;
  return (unsigned short)r;
}
__device__ __forceinline__ float bflo(unsigned u) {
  union { unsigned u; float f; } c; c.u = u << 16; return c.f;
}
__device__ __forceinline__ float bfhi(unsigned u) {
  union { unsigned u; float f; } c; c.u = u & 0xFFFF0000u; return c.f;
}

// ---------------- CSR build ----------------
__global__ void k_count(const int* __restrict__ dst, int* __restrict__ deg) {
  int e = blockIdx.x * 256 + threadIdx.x;
  if (e < NUM_EDGES) atomicAdd(&deg[dst[e]], 1);
}

__global__ __launch_bounds__(1024) void k_scan(const int* __restrict__ deg, int* __restrict__ off) {
  __shared__ int part[1024];
  int t = threadIdx.x;
  int base = t * 32;
  int4 d[8];
  const int4* dp = (const int4*)(deg + base);
  #pragma unroll
  for (int i = 0; i < 8; i++) d[i] = dp[i];
  int s = 0;
  #pragma unroll
  for (int i = 0; i < 8; i++) s += d[i].x + d[i].y + d[i].z + d[i].w;
  part[t] = s;
  __syncthreads();
  for (int dd = 1; dd < 1024; dd <<= 1) {
    int v = (t >= dd) ? part[t - dd] : 0;
    __syncthreads();
    part[t] += v;
    __syncthreads();
  }
  int run = (t == 0) ? 0 : part[t - 1];
  int4* op = (int4*)(off + base);
  #pragma unroll
  for (int i = 0; i < 8; i++) {
    int4 o;
    o.x = run; run += d[i].x;
    o.y = run; run += d[i].y;
    o.z = run; run += d[i].z;
    o.w = run; run += d[i].w;
    op[i] = o;
  }
}

__global__ void k_fill(const int* __restrict__ src, const int* __restrict__ dst,
                       const int* __restrict__ off, int* __restrict__ cur,
                       int* __restrict__ csr) {
  int e = blockIdx.x * 256 + threadIdx.x;
  if (e < NUM_EDGES) {
    int d = dst[e];
    int p = atomicAdd(&cur[d], 1);
    csr[off[d] + p] = src[e];
  }
}

// ---------------- pre-convert weights to bf16 W^T, pre-swizzled LDS layout ----------------
__global__ __launch_bounds__(256) void k_prep(const float* __restrict__ W_in,
    const float* __restrict__ Wl, const float* __restrict__ Wr,
    char* __restrict__ winT, char* __restrict__ wlrT) {
  int bid = blockIdx.x;
  int tid = threadIdx.x;
  int col = tid & 127, hh = tid >> 7;
  if (bid < 4) {
    int q = bid;
    float w0[10], w1[10];
    #pragma unroll
    for (int i = 0; i < 10; i++) {
      int p = 2 * (q * 10 + i) + hh;
      w0[i] = (2 * p < D_IN) ? W_in[(size_t)(2 * p) * C + col] : 0.f;
      w1[i] = (2 * p + 1 < D_IN) ? W_in[(size_t)(2 * p + 1) * C + col] : 0.f;
    }
    #pragma unroll
    for (int i = 0; i < 10; i++) {
      int p = 2 * (q * 10 + i) + hh;
      unsigned pkv = ((unsigned)f2bf(w1[i]) << 16) | f2bf(w0[i]);
      int byte = col * 320 + ((4 * p) ^ (((col >> 1) & 3) << 4));
      *(unsigned*)(winT + byte) = pkv;
    }
  } else {
    int id = bid - 4;
    int m = id >> 2;
    int q = id & 3;
    int l = m >> 1, r = m & 1;
    const float* W = (r ? Wr : Wl) + (size_t)l * C * C;
    char* dst = wlrT + (size_t)m * 32768;
    float w0[8], w1[8];
    #pragma unroll
    for (int i = 0; i < 8; i++) {
      int p = 2 * (q * 8 + i) + hh;
      w0[i] = W[(size_t)(2 * p) * C + col];
      w1[i] = W[(size_t)(2 * p + 1) * C + col];
    }
    #pragma unroll
    for (int i = 0; i < 8; i++) {
      int p = 2 * (q * 8 + i) + hh;
      unsigned pkv = ((unsigned)f2bf(w1[i]) << 16) | f2bf(w0[i]);
      int byte = col * 256 + ((4 * p) ^ ((col & 7) << 4));
      *(unsigned*)(dst + byte) = pkv;
    }
  }
}

// ---------------- h = x @ W_in + b_in via MFMA + fused BN partial stats ----------------
__global__ __launch_bounds__(256) void k_lin_mfma(const float* __restrict__ x,
    const char* __restrict__ winT, const float* __restrict__ bias,
    float* __restrict__ h, float* __restrict__ part) {
  __shared__ __align__(16) char smem[61440];
  __shared__ float lsum[128];
  __shared__ float lsum2[128];
  char* tA = smem;
  char* tB = smem + 20480;
  int n0 = blockIdx.x * 64;
  int tid = threadIdx.x;
  if (tid < 128) { lsum[tid] = 0.f; lsum2[tid] = 0.f; }
  {
    float4 xv[10];
    #pragma unroll
    for (int k = 0; k < 10; k++) {
      int idx = k * 256 + tid;
      int row = idx / 40, j = idx - row * 40;
      xv[k] = (j < 36) ? *(const float4*)&x[(size_t)(n0 + row) * D_IN + 4 * j]
                       : (float4){0.f, 0.f, 0.f, 0.f};
    }
    #pragma unroll
    for (int k = 0; k < 10; k++) {
      int idx = k * 256 + tid;
      int row = idx / 40, j = idx - row * 40;
      uint2 pk;
      pk.x = ((unsigned)f2bf(xv[k].y) << 16) | f2bf(xv[k].x);
      pk.y = ((unsigned)f2bf(xv[k].w) << 16) | f2bf(xv[k].z);
      int byte = row * 320 + ((8 * j) ^ (((row >> 1) & 3) << 4));
      *(uint2*)(tA + byte) = pk;
    }
  }
  {
    const uint4* src = (const uint4*)winT;
    uint4* d = (uint4*)tB;
    uint4 v[10];
    #pragma unroll
    for (int k = 0; k < 10; k++) v[k] = src[k * 256 + tid];
    #pragma unroll
    for (int k = 0; k < 10; k++) d[k * 256 + tid] = v[k];
  }
  __syncthreads();
  int l = tid & 63, w = tid >> 6;
  f32x4 acc[8];
  #pragma unroll
  for (int f = 0; f < 8; f++) acc[f] = (f32x4){0.f, 0.f, 0.f, 0.f};
  int arow = w * 16 + (l & 15);
  #pragma unroll
  for (int ks = 0; ks < 5; ks++) {
    int kb = ks * 64 + (l >> 4) * 16;
    short8 a = *(const short8*)(tA + arow * 320 + (kb ^ (((arow >> 1) & 3) << 4)));
    #pragma unroll
    for (int f = 0; f < 8; f++) {
      int col = f * 16 + (l & 15);
      short8 b = *(const short8*)(tB + col * 320 + (kb ^ (((col >> 1) & 3) << 4)));
      acc[f] = __builtin_amdgcn_mfma_f32_16x16x32_bf16(a, b, acc[f], 0, 0, 0);
    }
  }
  int rowb = n0 + w * 16 + (l >> 4) * 4;
  #pragma unroll
  for (int f = 0; f < 8; f++) {
    int col = f * 16 + (l & 15);
    float bv = bias[col];
    float s = 0.f, s2 = 0.f;
    #pragma unroll
    for (int r = 0; r < 4; r++) {
      float v = acc[f][r] + bv;
      h[(size_t)(rowb + r) * C + col] = v;
      s += v; s2 += v * v;
    }
    s  += __shfl_xor(s, 16, 64);  s  += __shfl_xor(s, 32, 64);
    s2 += __shfl_xor(s2, 16, 64); s2 += __shfl_xor(s2, 32, 64);
    if (l < 16) {
      atomicAdd(&lsum[col], s);
      atomicAdd(&lsum2[col], s2);
    }
  }
  __syncthreads();
  if (tid < 128) {
    int bin = blockIdx.x & (NBINS - 1);
    atomicAdd(&part[bin * 256 + tid], lsum[tid]);
    atomicAdd(&part[bin * 256 + 128 + tid], lsum2[tid]);
  }
}

// ---------------- BN partial stats for layers 1..: accumulate into 32-bin layout ----------------
__global__ __launch_bounds__(128) void k_bn_part(const float* __restrict__ h, float* __restrict__ part) {
  int b = blockIdx.x; int c = threadIdx.x;
  float s = 0.f, s2 = 0.f;
  int r0 = b * 64;
  for (int r = 0; r < 64; r++) {
    float v = h[(size_t)(r0 + r) * C + c];
    s += v; s2 += v * v;
  }
  int bin = b & (NBINS - 1);
  atomicAdd(&part[bin * 256 + c], s);
  atomicAdd(&part[bin * 256 + 128 + c], s2);
}

// ---------------- BN finalize: reduce 32 bins -> sc/sh, re-zero bins ----------------
__global__ __launch_bounds__(256) void k_bn_fin(float* __restrict__ part,
    const float* __restrict__ gamma, const float* __restrict__ beta,
    float* __restrict__ sc, float* __restrict__ sh) {
  int tid = threadIdx.x;
  if (tid < 128) {
    double S = 0.0, S2 = 0.0;
    for (int b = 0; b < NBINS; b++) {
      S += (double)part[b * 256 + tid];
      S2 += (double)part[b * 256 + 128 + tid];
    }
    double m = S / (double)N_NODES;
    double var = S2 / (double)N_NODES - m * m;
    float rsig = (float)(1.0 / sqrt(var + 1e-5));
    float scv = rsig * gamma[tid];
    sc[tid] = scv;
    sh[tid] = beta[tid] - (float)m * scv;
  }
  __syncthreads();
  for (int i = tid; i < NBINS * 256; i += 256) part[i] = 0.f;
}

// ---------------- fused: t = leaky(bn(h)); xl = t@Wl+bl; xr = t@Wr+br ----------------
__device__ __forceinline__ void gemm_half(const char* tA, const char* tB,
    const float* bias, unsigned short* out, int n0, int tid) {
  int l = tid & 63, w = tid >> 6;
  f32x4 acc[8];
  #pragma unroll
  for (int f = 0; f < 8; f++) acc[f] = (f32x4){0.f, 0.f, 0.f, 0.f};
  int arow = w * 16 + (l & 15);
  #pragma unroll
  for (int ks = 0; ks < 4; ks++) {
    int kb = ks * 64 + (l >> 4) * 16;
    short8 a = *(const short8*)(tA + arow * 256 + (kb ^ ((arow & 7) << 4)));
    #pragma unroll
    for (int f = 0; f < 8; f++) {
      int col = f * 16 + (l & 15);
      short8 b = *(const short8*)(tB + col * 256 + (kb ^ ((col & 7) << 4)));
      acc[f] = __builtin_amdgcn_mfma_f32_16x16x32_bf16(a, b, acc[f], 0, 0, 0);
    }
  }
  int rowb = n0 + w * 16 + (l >> 4) * 4;
  #pragma unroll
  for (int f = 0; f < 8; f++) {
    int col = f * 16 + (l & 15);
    float bv = bias[col];
    #pragma unroll
    for (int r = 0; r < 4; r++)
      out[(size_t)(rowb + r) * C + col] = f2bf(acc[f][r] + bv);
  }
}

__device__ __forceinline__ void copy_B(char* tB, const char* __restrict__ WT, int tid) {
  const uint4* src = (const uint4*)WT;
  uint4* d = (uint4*)tB;
  uint4 v[8];
  #pragma unroll
  for (int k = 0; k < 8; k++) v[k] = src[k * 256 + tid];
  #pragma unroll
  for (int k = 0; k < 8; k++) d[k * 256 + tid] = v[k];
}

__global__ __launch_bounds__(256) void k_gemm_mfma(const float* __restrict__ h,
    const float* __restrict__ sc, const float* __restrict__ sh,
    const char* __restrict__ WlT, const float* __restrict__ bl,
    const char* __restrict__ WrT, const float* __restrict__ br,
    unsigned short* __restrict__ xl, unsigned short* __restrict__ xr) {
  __shared__ __align__(16) char smem[49152];
  char* tA = smem;
  char* tB = smem + 16384;
  int n0 = blockIdx.x * 64;
  int tid = threadIdx.x;
  {
    int cp = tid & 63, w4 = tid >> 6;
    float2 scv = *(const float2*)&sc[2 * cp];
    float2 shv = *(const float2*)&sh[2 * cp];
    float2 hv[16];
    #pragma unroll
    for (int t = 0; t < 16; t++)
      hv[t] = *(const float2*)&h[(size_t)(n0 + t * 4 + w4) * C + 2 * cp];
    #pragma unroll
    for (int t = 0; t < 16; t++) {
      int node = t * 4 + w4;
      float t0 = hv[t].x * scv.x + shv.x; t0 = fmaxf(t0, 0.01f * t0);
      float t1 = hv[t].y * scv.y + shv.y; t1 = fmaxf(t1, 0.01f * t1);
      unsigned pkv = ((unsigned)f2bf(t1) << 16) | f2bf(t0);
      int byte = node * 256 + ((4 * cp) ^ ((node & 7) << 4));
      *(unsigned*)(tA + byte) = pkv;
    }
  }
  copy_B(tB, WlT, tid);
  __syncthreads();
  gemm_half(tA, tB, bl, xl, n0, tid);
  __syncthreads();
  copy_B(tB, WrT, tid);
  __syncthreads();
  gemm_half(tA, tB, br, xr, n0, tid);
}

// ---------------- fused GATv2: 2 nodes/wave, shuffle-broadcast CSR, defer-max ----------------
#define GAT_EDGE(te, ya, yb, yc, yd)                                       \
  if ((te) > m + 8.f) {                                                    \
    float f_ = __expf(m - (te));                                           \
    ssum = fmaf(ssum, f_, 1.f);                                            \
    acc0 = fmaf(acc0, f_, (ya)); acc1 = fmaf(acc1, f_, (yb));              \
    acc2 = fmaf(acc2, f_, (yc)); acc3 = fmaf(acc3, f_, (yd));              \
    m = (te);                                                              \
  } else {                                                                 \
    float p_ = __expf((te) - m);                                           \
    ssum += p_;                                                            \
    acc0 = fmaf(p_, (ya), acc0); acc1 = fmaf(p_, (yb), acc1);              \
    acc2 = fmaf(p_, (yc), acc2); acc3 = fmaf(p_, (yd), acc3);              \
  }

__global__ __launch_bounds__(256) void k_gat(float* __restrict__ h,
    const unsigned* __restrict__ xlb, const unsigned* __restrict__ xrb,
    const float* __restrict__ att, const float* __restrict__ cb,
    const int* __restrict__ off, const int* __restrict__ deg,
    const int* __restrict__ csr) {
  int tid = threadIdx.x;
  int lane = tid & 63;
  int w = tid >> 6;
  int half = lane >> 5;
  int q = lane & 31;
  int node = blockIdx.x * 8 + w * 2 + half;
  float4 a = *(const float4*)&att[q * 4];
  uint2 ur = *(const uint2*)&xrb[(size_t)node * 64 + q * 2];
  float xr0 = bflo(ur.x), xr1 = bfhi(ur.x), xr2 = bflo(ur.y), xr3 = bfhi(ur.y);
  uint2 us = *(const uint2*)&xlb[(size_t)node * 64 + q * 2];
  float acc0 = bflo(us.x), acc1 = bfhi(us.x), acc2 = bflo(us.y), acc3 = bfhi(us.y);
  float p0 = lrelu2(acc0 + xr0) * a.x + lrelu2(acc1 + xr1) * a.y
           + lrelu2(acc2 + xr2) * a.z + lrelu2(acc3 + xr3) * a.w;
  #pragma unroll
  for (int mm = 1; mm < 32; mm <<= 1) p0 += __shfl_xor(p0, mm, 64);
  float m = p0;
  float ssum = 1.f;
  int o = off[node], dg = deg[node];
  int dgmax = max(dg, __shfl_xor(dg, 32, 64));
  for (int base = 0; base < dgmax; base += 32) {
    // one coalesced vector load covers up to 32 edge indices for this half
    int cv = (q < dg - base) ? csr[o + base + q] : 0;
    int nb = min(dgmax - base, 32);
    for (int j = 0; j < nb; j += 4) {
      int s0 = __shfl(cv, (half << 5) + j + 0, 64);
      int s1 = __shfl(cv, (half << 5) + j + 1, 64);
      int s2 = __shfl(cv, (half << 5) + j + 2, 64);
      int s3 = __shfl(cv, (half << 5) + j + 3, 64);
      uint2 u0 = *(const uint2*)&xlb[(size_t)s0 * 64 + q * 2];
      uint2 u1 = *(const uint2*)&xlb[(size_t)s1 * 64 + q * 2];
      uint2 u2 = *(const uint2*)&xlb[(size_t)s2 * 64 + q * 2];
      uint2 u3 = *(const uint2*)&xlb[(size_t)s3 * 64 + q * 2];
      float y00 = bflo(u0.x), y01 = bfhi(u0.x), y02 = bflo(u0.y), y03 = bfhi(u0.y);
      float y10 = bflo(u1.x), y11 = bfhi(u1.x), y12 = bflo(u1.y), y13 = bfhi(u1.y);
      float y20 = bflo(u2.x), y21 = bfhi(u2.x), y22 = bflo(u2.y), y23 = bfhi(u2.y);
      float y30 = bflo(u3.x), y31 = bfhi(u3.x), y32 = bflo(u3.y), y33 = bfhi(u3.y);
      float t0 = lrelu2(y00 + xr0) * a.x + lrelu2(y01 + xr1) * a.y
               + lrelu2(y02 + xr2) * a.z + lrelu2(y03 + xr3) * a.w;
      float t1 = lrelu2(y10 + xr0) * a.x + lrelu2(y11 + xr1) * a.y
               + lrelu2(y12 + xr2) * a.z + lrelu2(y13 + xr3) * a.w;
      float t2 = lrelu2(y20 + xr0) * a.x + lrelu2(y21 + xr1) * a.y
               + lrelu2(y22 + xr2) * a.z + lrelu2(y23 + xr3) * a.w;
      float t3 = lrelu2(y30 + xr0) * a.x + lrelu2(y31 + xr1) * a.y
               + lrelu2(y32 + xr2) * a.z + lrelu2(y33 + xr3) * a.w;
      #pragma unroll
      for (int mm = 1; mm < 32; mm <<= 1) {
        t0 += __shfl_xor(t0, mm, 64);
        t1 += __shfl_xor(t1, mm, 64);
        t2 += __shfl_xor(t2, mm, 64);
        t3 += __shfl_xor(t3, mm, 64);
      }
      int jb = base + j;
      t0 = (jb + 0 < dg) ? t0 : -1e30f;
      t1 = (jb + 1 < dg) ? t1 : -1e30f;
      t2 = (jb + 2 < dg) ? t2 : -1e30f;
      t3 = (jb + 3 < dg) ? t3 : -1e30f;
      GAT_EDGE(t0, y00, y01, y02, y03);
      GAT_EDGE(t1, y10, y11, y12, y13);
      GAT_EDGE(t2, y20, y21, y22, y23);
      GAT_EDGE(t3, y30, y31, y32, y33);
    }
  }
  float inv = 1.f / ssum;
  float4 cbv = *(const float4*)&cb[q * 4];
  float4 hv = *(float4*)&h[(size_t)node * C + q * 4];
  hv.x += acc0 * inv + cbv.x;
  hv.y += acc1 * inv + cbv.y;
  hv.z += acc2 * inv + cbv.z;
  hv.w += acc3 * inv + cbv.w;
  *(float4*)&h[(size_t)node * C + q * 4] = hv;
}

// ---------------- mem-pool 1 ----------------
__global__ __launch_bounds__(320) void k_mem1(const float* __restrict__ h,
    const float* __restrict__ K1, float* __restrict__ S1, float* __restrict__ colsum) {
  __shared__ float dd[64 * 51];
  __shared__ float kn[50];
  int tid = threadIdx.x;
  int lane = tid & 63;
  int w = tid >> 6;
  int n0 = blockIdx.x * 64;
  if (tid < 50) {
    const float4* kr = reinterpret_cast<const float4*>(K1 + tid * C);
    float s = 0.f;
    for (int q = 0; q < 32; q++) {
      float4 kv = kr[q];
      s += kv.x * kv.x + kv.y * kv.y + kv.z * kv.z + kv.w * kv.w;
    }
    kn[tid] = s;
  }
  int wu = __builtin_amdgcn_readfirstlane(w);
  const float4* x4 = reinterpret_cast<const float4*>(h + (size_t)(n0 + lane) * C);
  const float4* K4 = reinterpret_cast<const float4*>(K1);
  float acc[10];
  #pragma unroll
  for (int it = 0; it < 10; it++) acc[it] = 0.f;
  float xn = 0.f;
  for (int q = 0; q < 32; q += 2) {
    float4 xa = x4[q], xb = x4[q + 1];
    xn += xa.x * xa.x + xa.y * xa.y + xa.z * xa.z + xa.w * xa.w
        + xb.x * xb.x + xb.y * xb.y + xb.z * xb.z + xb.w * xb.w;
    #pragma unroll
    for (int it = 0; it < 10; it++) {
      int j = wu + 5 * it;
      float4 ka = K4[j * 32 + q], kb = K4[j * 32 + q + 1];
      acc[it] += xa.x * ka.x + xa.y * ka.y + xa.z * ka.z + xa.w * ka.w
               + xb.x * kb.x + xb.y * kb.y + xb.z * kb.z + xb.w * kb.w;
    }
  }
  #pragma unroll
  for (int it = 0; it < 10; it++) dd[lane * 51 + wu + 5 * it] = acc[it];
  __syncthreads();
  if (tid < 64) {
    float sn[10];
    #pragma unroll
    for (int k = 0; k < 10; k++) sn[k] = 0.f;
    #pragma unroll
    for (int hd = 0; hd < 5; hd++) {
      float sh_[10]; float hs = 0.f;
      #pragma unroll
      for (int k = 0; k < 10; k++) {
        int j = hd * 10 + k;
        float dist = xn + kn[j] - 2.f * dd[tid * 51 + j];
        float s = 1.f / (1.f + dist);
        sh_[k] = s; hs += s;
      }
      float inv = 1.f / hs;
      #pragma unroll
      for (int k = 0; k < 10; k++) sn[k] += sh_[k] * inv;
    }
    int b = n0 >> 10;
    #pragma unroll
    for (int k = 0; k < 10; k++) {
      float v = 0.2f * sn[k];
      S1[(n0 + tid) * 10 + k] = v;
      float vs = wave_sum(v);
      if (tid == 0) atomicAdd(&colsum[b * 10 + k], vs);
    }
  }
}

// ---------------- pooled features: partial S1^T @ xd ----------------
__global__ __launch_bounds__(128) void k_pool1a(const float* __restrict__ h,
    const float* __restrict__ S1, float* __restrict__ pp) {
  int b = blockIdx.x >> 5, ch = blockIdx.x & 31;
  int c = threadIdx.x;
  float acc[10];
  #pragma unroll
  for (int k = 0; k < 10; k++) acc[k] = 0.f;
  int n0 = ch * 32;
  for (int n = 0; n < 32; n++) {
    int i = b * PER_G + n0 + n;
    float xv = h[(size_t)i * C + c];
    #pragma unroll
    for (int k = 0; k < 10; k++) acc[k] += S1[i * 10 + k] * xv;
  }
  #pragma unroll
  for (int k = 0; k < 10; k++) pp[(size_t)((b * 32 + ch) * 10 + k) * C + c] = acc[k];
}

// ---------------- reduce partials, apply Wm1 + leaky -> x1 ----------------
__global__ __launch_bounds__(128) void k_pool1b(const float* __restrict__ pp,
    const float* __restrict__ Wm1, float* __restrict__ x1) {
  int bk = blockIdx.x; int b = bk / 10; int k = bk - b * 10;
  int c = threadIdx.x;
  __shared__ float red[C];
  float r = 0.f;
  for (int ch = 0; ch < 32; ch++) r += pp[(size_t)((b * 32 + ch) * 10 + k) * C + c];
  red[c] = r;
  __syncthreads();
  if (c < C_MID) {
    float o = 0.f;
    for (int mIdx = 0; mIdx < C; mIdx++) o += red[mIdx] * Wm1[mIdx * C_MID + c];
    o = fmaxf(o, 0.01f * o);
    x1[bk * C_MID + c] = o;
  }
}

// ---------------- KL(S1) ----------------
__global__ __launch_bounds__(256) void k_kl1(const float* __restrict__ S1,
    const float* __restrict__ colsum, float* __restrict__ kl) {
  int i = blockIdx.x * 256 + threadIdx.x;
  int b = i >> 10;
  float s[10], q[10];
  float den = 0.f;
  #pragma unroll
  for (int k = 0; k < 10; k++) {
    s[k] = S1[i * 10 + k];
    q[k] = s[k] * s[k] / colsum[b * 10 + k];
    den += q[k];
  }
  float inv = 1.f / den;
  float term = 0.f;
  #pragma unroll
  for (int k = 0; k < 10; k++) {
    float P = fmaxf(q[k] * inv, 1e-15f);
    float Sc = fmaxf(s[k], 1e-15f);
    term += P * (logf(P) - logf(Sc));
  }
  term *= (1.f / (float)NUM_GRAPHS);
  term = wave_sum(term);
  if ((threadIdx.x & 63) == 0) atomicAdd(kl, term);
}

// ---------------- mem-pool 2 (S2==1) + log_softmax + kl write ----------------
__global__ __launch_bounds__(128) void k_mem2(const float* __restrict__ x1,
    const float* __restrict__ Wm2, const float* __restrict__ kl, float* __restrict__ out) {
  int b = blockIdx.x;
  __shared__ float t80[C_MID];
  int tid = threadIdx.x;
  if (tid < C_MID) {
    float s = 0.f;
    #pragma unroll
    for (int k = 0; k < 10; k++) s += x1[(b * 10 + k) * C_MID + tid];
    t80[tid] = s;
  }
  __syncthreads();
  if (tid < C_OUT) {
    float o = 0.f;
    for (int mIdx = 0; mIdx < C_MID; mIdx++) o += t80[mIdx] * Wm2[mIdx * C_OUT + tid];
    float mx = o;
    #pragma unroll
    for (int d = 1; d < 64; d <<= 1) mx = fmaxf(mx, __shfl_xor(mx, d, 64));
    float p = expf(o - mx);
    float sum = p;
    #pragma unroll
    for (int d = 1; d < 64; d <<= 1) sum += __shfl_xor(sum, d, 64);
    out[b * C_OUT + tid] = o - mx - logf(sum);
  }
  if (b == 0 && tid == 127) out[NUM_GRAPHS * C_OUT] = kl[0];
}

extern "C" void kernel_launch(void* const* d_in, const int* in_sizes, int n_in,
                              void* d_out, int out_size, void* d_ws, size_t ws_size,
                              hipStream_t stream) {
  const float* x    = (const float*)d_in[0];
  const int*   ei   = (const int*)d_in[1];
  const float* W_in = (const float*)d_in[3];
  const float* b_in = (const float*)d_in[4];
  const float* bn_g = (const float*)d_in[5];
  const float* bn_b = (const float*)d_in[6];
  const float* Wl   = (const float*)d_in[7];
  const float* bl   = (const float*)d_in[8];
  const float* Wr   = (const float*)d_in[9];
  const float* br   = (const float*)d_in[10];
  const float* att  = (const float*)d_in[11];
  const float* cb   = (const float*)d_in[12];
  const float* K1   = (const float*)d_in[13];
  const float* Wm1  = (const float*)d_in[14];
  const float* Wm2  = (const float*)d_in[16];
  float* out = (float*)d_out;

  char* ws = (char*)d_ws;
  float* h    = (float*)(ws + WS_H);
  unsigned short* xlp = (unsigned short*)(ws + WS_XL);
  unsigned short* xrp = (unsigned short*)(ws + WS_XR);
  int*   csr  = (int*)(ws + WS_CSR);
  int*   deg  = (int*)(ws + WS_DEG);
  int*   off  = (int*)(ws + WS_OFF);
  int*   cur  = (int*)(ws + WS_CUR);
  float* part = (float*)(ws + WS_PART);
  float* scv  = (float*)(ws + WS_SC);
  float* shv  = (float*)(ws + WS_SH);
  float* S1p  = (float*)(ws + WS_S1);
  float* cs   = (float*)(ws + WS_CS);
  float* pp   = (float*)(ws + WS_PP);
  float* x1p  = (float*)(ws + WS_X1);
  float* klp  = (float*)(ws + WS_KL);
  char*  winT = ws + WS_WINT;
  char*  wlrT = ws + WS_WLRT;

  const int* srcp = ei;
  const int* dstp = ei + NUM_EDGES;

  hipMemsetAsync(ws + WS_ZERO_BASE, 0, WS_ZERO_SIZE, stream);

  k_prep<<<28, 256, 0, stream>>>(W_in, Wl, Wr, winT, wlrT);
  k_count<<<NUM_EDGES / 256, 256, 0, stream>>>(dstp, deg);
  k_scan<<<1, 1024, 0, stream>>>(deg, off);
  k_fill<<<NUM_EDGES / 256, 256, 0, stream>>>(srcp, dstp, off, cur, csr);

  k_lin_mfma<<<N_NODES / 64, 256, 0, stream>>>(x, winT, b_in, h, part);

  for (int l = 0; l < NL; l++) {
    if (l > 0) k_bn_part<<<N_NODES / 64, 128, 0, stream>>>(h, part);
    k_bn_fin<<<1, 256, 0, stream>>>(part, bn_g + l * C, bn_b + l * C, scv, shv);
    k_gemm_mfma<<<N_NODES / 64, 256, 0, stream>>>(h, scv, shv,
        wlrT + (size_t)(l * 2) * 32768, bl + l * C,
        wlrT + (size_t)(l * 2 + 1) * 32768, br + l * C,
        xlp, xrp);
    k_gat<<<N_NODES / 8, 256, 0, stream>>>(h, (const unsigned*)xlp, (const unsigned*)xrp,
        att + l * C, cb + l * C, off, deg, csr);
  }

  k_mem1<<<N_NODES / 64, 320, 0, stream>>>(h, K1, S1p, cs);
  k_pool1a<<<NUM_GRAPHS * 32, 128, 0, stream>>>(h, S1p, pp);
  k_pool1b<<<NUM_GRAPHS * 10, 128, 0, stream>>>(pp, Wm1, x1p);
  k_kl1<<<N_NODES / 256, 256, 0, stream>>>(S1p, cs, klp);
  k_mem2<<<NUM_GRAPHS, 128, 0, stream>>>(x1p, Wm2, klp, out);
}